// Round 4
// baseline (102.267 us; speedup 1.0000x reference)
//
#include <hip/hip_runtime.h>

#define NBINS 15
#define RB 11            // reachable bins: conf in (1/3-eps, 1] -> bins 4..14
#define BIN_LO 4
#define GRID 2048
#define BLOCK 256
#define NWAVE (BLOCK / 64)

// Per-row: d(bin) += (conf - acc).  ECE = sum_b |d_b| / N.
// Histogram: per-THREAD-private LDS columns h[bin][tid]. ds_add_f32 to 64
// distinct addresses per wave (bank = tid%32, fixed 2-way = free), no
// same-address serialization (R3's failure), no RMW latency chain.
__global__ __launch_bounds__(BLOCK) void ece_main(
    const float* __restrict__ logits,
    const int* __restrict__ labels,
    float* __restrict__ part,      // [RB][GRID] partials (or RB atomics)
    long long ngroups, long long nrows, int use_atomic)
{
    __shared__ float h[RB][BLOCK];
#pragma unroll
    for (int b = 0; b < RB; ++b) h[b][threadIdx.x] = 0.0f;
    __syncthreads();

    float* hcol = &h[0][threadIdx.x];   // column base; row stride = BLOCK

    auto proc = [&](float l0, float l1, float l2, int lab) {
        float m = fmaxf(fmaxf(l0, l1), l2);          // v_max3_f32
        // conf = 1 / sum(exp(l - m)); one exp is exp(0)=1 exactly
        float s = __expf(l0 - m) + __expf(l1 - m) + __expf(l2 - m);
        float conf = __builtin_amdgcn_rcpf(s);
        // accuracy: label's logit equals the max (ties: measure-zero, <2/N ECE)
        float ll = (lab == 1) ? l1 : l0;
        ll = (lab == 2) ? l2 : ll;
        float x = (ll == m) ? conf - 1.0f : conf;    // conf - acc
        // bin = floor(conf*15) in [4,14] -> idx in [0,10]
        int idx = (int)__builtin_fmaf(conf, 15.0f, (float)(-BIN_LO));
        idx = idx < 0 ? 0 : (idx > RB - 1 ? RB - 1 : idx);  // v_med3-able
        atomicAdd(hcol + idx * BLOCK, x);            // ds_add_f32, lane-private
    };

    const float4* __restrict__ L4  = (const float4*)logits;
    const int4*  __restrict__  Lb4 = (const int4*)labels;

    long long tid    = (long long)blockIdx.x * blockDim.x + threadIdx.x;
    long long stride = (long long)gridDim.x * blockDim.x;
#pragma unroll 2
    for (long long g = tid; g < ngroups; g += stride) {
        float4 a = L4[3 * g + 0];
        float4 b = L4[3 * g + 1];
        float4 c = L4[3 * g + 2];
        int4 lb  = Lb4[g];
        // rows: [a.x a.y a.z] [a.w b.x b.y] [b.z b.w c.x] [c.y c.z c.w]
        proc(a.x, a.y, a.z, lb.x);
        proc(a.w, b.x, b.y, lb.y);
        proc(b.z, b.w, c.x, lb.z);
        proc(c.y, c.z, c.w, lb.w);
    }
    // remainder rows (N % 4 != 0) — one thread, same private column
    if (tid == 0) {
        for (long long r = ngroups * 4; r < nrows; ++r)
            proc(logits[3 * r], logits[3 * r + 1], logits[3 * r + 2],
                 labels[r]);
    }

    __syncthreads();
    // each thread reduces its own column via wave shuffle, then cross-wave
    float d[RB];
#pragma unroll
    for (int b = 0; b < RB; ++b) d[b] = h[b][threadIdx.x];
#pragma unroll
    for (int b = 0; b < RB; ++b)
#pragma unroll
        for (int off = 32; off > 0; off >>= 1)
            d[b] += __shfl_down(d[b], off, 64);

    __syncthreads();   // h reuse below
    __shared__ float sred[NWAVE][RB];
    int wave = threadIdx.x >> 6, lane = threadIdx.x & 63;
    if (lane == 0)
#pragma unroll
        for (int b = 0; b < RB; ++b) sred[wave][b] = d[b];
    __syncthreads();
    if (threadIdx.x < RB) {
        float v = sred[0][threadIdx.x] + sred[1][threadIdx.x] +
                  sred[2][threadIdx.x] + sred[3][threadIdx.x];
        if (use_atomic)
            atomicAdd(&part[threadIdx.x], v);
        else
            part[(long long)threadIdx.x * gridDim.x + blockIdx.x] = v;
    }
}

__global__ __launch_bounds__(BLOCK) void ece_final(
    const float* __restrict__ part, float* __restrict__ out,
    float invN, int grid, int use_atomic)
{
    if (use_atomic) {
        if (threadIdx.x == 0) {
            float e = 0.0f;
#pragma unroll
            for (int b = 0; b < RB; ++b) e += fabsf(part[b]);
            out[0] = e * invN;
        }
        return;
    }
    float v[RB];
#pragma unroll
    for (int b = 0; b < RB; ++b) v[b] = 0.0f;
    for (int i = threadIdx.x; i < grid; i += BLOCK) {
#pragma unroll
        for (int b = 0; b < RB; ++b) v[b] += part[(long long)b * grid + i];
    }
#pragma unroll
    for (int b = 0; b < RB; ++b)
#pragma unroll
        for (int off = 32; off > 0; off >>= 1)
            v[b] += __shfl_down(v[b], off, 64);
    __shared__ float sred[BLOCK / 64][RB];
    int wave = threadIdx.x >> 6, lane = threadIdx.x & 63;
    if (lane == 0)
#pragma unroll
        for (int b = 0; b < RB; ++b) sred[wave][b] = v[b];
    __syncthreads();
    if (threadIdx.x == 0) {
        float e = 0.0f;
#pragma unroll
        for (int b = 0; b < RB; ++b)
            e += fabsf(sred[0][b] + sred[1][b] + sred[2][b] + sred[3][b]);
        out[0] = e * invN;
    }
}

extern "C" void kernel_launch(void* const* d_in, const int* in_sizes, int n_in,
                              void* d_out, int out_size, void* d_ws, size_t ws_size,
                              hipStream_t stream) {
    const float* logits = (const float*)d_in[0];
    const int*   labels = (const int*)d_in[1];
    float* out  = (float*)d_out;
    float* ws   = (float*)d_ws;

    long long N = in_sizes[1];          // labels count = row count
    long long ngroups = N / 4;

    size_t need = (size_t)RB * GRID * sizeof(float);
    int use_atomic = (ws_size < need) ? 1 : 0;

    if (use_atomic)  // fallback path only: zero the 11-float accumulator
        hipMemsetAsync(ws, 0, RB * sizeof(float), stream);

    ece_main<<<GRID, BLOCK, 0, stream>>>(logits, labels, ws, ngroups, N,
                                         use_atomic);
    ece_final<<<1, BLOCK, 0, stream>>>(ws, out, 1.0f / (float)N, GRID,
                                       use_atomic);
}

// Round 5
// 54.191 us; speedup vs baseline: 1.8872x; 1.8872x over previous
//
#include <hip/hip_runtime.h>

#define NBINS 15
#define RB 11            // reachable bins: conf in (1/3-eps, 1] -> bins 4..14
#define BIN_LO 4
#define GRID 2048
#define BLOCK 256
#define NWAVE (BLOCK / 64)

// Per-row contribution to bin(conf): x = conf - accuracy.
// ECE = sum_b |sum_{i in b} x_i| / N.
// Register predicated histogram (R2 structure — memory-bound champion);
// LDS atomics proven 2x worse (R3/R4: CAS-loop latency chain).
__device__ __forceinline__ void proc_row(float l0, float l1, float l2, int lab,
                                         float* d) {
    float m = fmaxf(fmaxf(l0, l1), l2);              // v_max3_f32
    // conf = max softmax prob = 1 / sum(exp(l - m)); one exp is exp(0)=1
    float s = __expf(l0 - m) + __expf(l1 - m) + __expf(l2 - m);
    float conf = __builtin_amdgcn_rcpf(s);           // v_rcp_f32
    // accuracy: label's logit equals the max (tie flips are measure-zero,
    // each costs <= 2/N in ECE — far under threshold)
    float ll = (lab == 1) ? l1 : l0;
    ll = (lab == 2) ? l2 : ll;
    float x = (ll == m) ? conf - 1.0f : conf;        // conf - acc
    // bin = floor(conf*15) in [4,14] -> idx in [0,10]
    int idx = (int)__builtin_fmaf(conf, 15.0f, (float)(-BIN_LO));
    idx = idx < 0 ? 0 : (idx > RB - 1 ? RB - 1 : idx);
#pragma unroll
    for (int b = 0; b < RB; ++b)
        d[b] += (idx == b) ? x : 0.0f;
}

__global__ __launch_bounds__(BLOCK) void ece_main(
    const float* __restrict__ logits,
    const int* __restrict__ labels,
    float* __restrict__ part,      // [RB][GRID] partials (or RB atomics)
    long long ngroups, long long nrows, int use_atomic)
{
    float d[RB];
#pragma unroll
    for (int b = 0; b < RB; ++b) d[b] = 0.0f;

    const float4* __restrict__ L4  = (const float4*)logits;
    const int4*  __restrict__  Lb4 = (const int4*)labels;

    long long tid    = (long long)blockIdx.x * blockDim.x + threadIdx.x;
    long long stride = (long long)gridDim.x * blockDim.x;
#pragma unroll 4
    for (long long g = tid; g < ngroups; g += stride) {
        float4 a = L4[3 * g + 0];
        float4 b = L4[3 * g + 1];
        float4 c = L4[3 * g + 2];
        int4 lb  = Lb4[g];
        // rows: [a.x a.y a.z] [a.w b.x b.y] [b.z b.w c.x] [c.y c.z c.w]
        proc_row(a.x, a.y, a.z, lb.x, d);
        proc_row(a.w, b.x, b.y, lb.y, d);
        proc_row(b.z, b.w, c.x, lb.z, d);
        proc_row(c.y, c.z, c.w, lb.w, d);
    }
    // remainder rows (N % 4 != 0) — one thread
    if (tid == 0) {
        for (long long r = ngroups * 4; r < nrows; ++r)
            proc_row(logits[3 * r], logits[3 * r + 1], logits[3 * r + 2],
                     labels[r], d);
    }

    // 64-lane shuffle reduction
#pragma unroll
    for (int b = 0; b < RB; ++b)
#pragma unroll
        for (int off = 32; off > 0; off >>= 1)
            d[b] += __shfl_down(d[b], off, 64);

    __shared__ float sred[NWAVE][RB];
    int wave = threadIdx.x >> 6, lane = threadIdx.x & 63;
    if (lane == 0)
#pragma unroll
        for (int b = 0; b < RB; ++b) sred[wave][b] = d[b];
    __syncthreads();
    if (threadIdx.x < RB) {
        float v = sred[0][threadIdx.x] + sred[1][threadIdx.x] +
                  sred[2][threadIdx.x] + sred[3][threadIdx.x];
        if (use_atomic)
            atomicAdd(&part[threadIdx.x], v);
        else
            part[(long long)threadIdx.x * gridDim.x + blockIdx.x] = v;
    }
}

__global__ __launch_bounds__(BLOCK) void ece_final(
    const float* __restrict__ part, float* __restrict__ out,
    float invN, int grid, int use_atomic)
{
    if (use_atomic) {
        if (threadIdx.x == 0) {
            float e = 0.0f;
#pragma unroll
            for (int b = 0; b < RB; ++b) e += fabsf(part[b]);
            out[0] = e * invN;
        }
        return;
    }
    float v[RB];
#pragma unroll
    for (int b = 0; b < RB; ++b) v[b] = 0.0f;
    for (int i = threadIdx.x; i < grid; i += BLOCK) {
#pragma unroll
        for (int b = 0; b < RB; ++b) v[b] += part[(long long)b * grid + i];
    }
#pragma unroll
    for (int b = 0; b < RB; ++b)
#pragma unroll
        for (int off = 32; off > 0; off >>= 1)
            v[b] += __shfl_down(v[b], off, 64);
    __shared__ float sred[NWAVE][RB];
    int wave = threadIdx.x >> 6, lane = threadIdx.x & 63;
    if (lane == 0)
#pragma unroll
        for (int b = 0; b < RB; ++b) sred[wave][b] = v[b];
    __syncthreads();
    if (threadIdx.x == 0) {
        float e = 0.0f;
#pragma unroll
        for (int b = 0; b < RB; ++b)
            e += fabsf(sred[0][b] + sred[1][b] + sred[2][b] + sred[3][b]);
        out[0] = e * invN;
    }
}

extern "C" void kernel_launch(void* const* d_in, const int* in_sizes, int n_in,
                              void* d_out, int out_size, void* d_ws, size_t ws_size,
                              hipStream_t stream) {
    const float* logits = (const float*)d_in[0];
    const int*   labels = (const int*)d_in[1];
    float* out  = (float*)d_out;
    float* ws   = (float*)d_ws;

    long long N = in_sizes[1];          // labels count = row count
    long long ngroups = N / 4;

    size_t need = (size_t)RB * GRID * sizeof(float);
    int use_atomic = (ws_size < need) ? 1 : 0;

    if (use_atomic)  // fallback path only: zero the 11-float accumulator
        hipMemsetAsync(ws, 0, RB * sizeof(float), stream);

    ece_main<<<GRID, BLOCK, 0, stream>>>(logits, labels, ws, ngroups, N,
                                         use_atomic);
    ece_final<<<1, BLOCK, 0, stream>>>(ws, out, 1.0f / (float)N, GRID,
                                       use_atomic);
}

// Round 7
// 52.037 us; speedup vs baseline: 1.9653x; 1.0414x over previous
//
#include <hip/hip_runtime.h>

#define NBINS 15
#define RB 11            // reachable bins: conf in (1/3-eps, 1] -> bins 4..14
#define BIN_LO 4
#define GRID 2048
#define BLOCK 256
#define NWAVE (BLOCK / 64)
#define FBLOCK 1024      // final-reduce block (16 waves)

// Per-row contribution to bin(conf): x = conf - accuracy.
// ECE = sum_b |sum_{i in b} x_i| / N.   (R2 champion structure.)
__device__ __forceinline__ void proc_row(float l0, float l1, float l2, int lab,
                                         float* d) {
    // argmax, first-occurrence tie-break (matches jnp.argmax)
    float m = l0; int p = 0;
    if (l1 > m) { m = l1; p = 1; }
    if (l2 > m) { m = l2; p = 2; }
    // conf = max softmax prob = 1 / sum(exp(l - m)); exp(0)=1 exact
    float s = __expf(l0 - m) + __expf(l1 - m) + __expf(l2 - m);
    float conf = __builtin_amdgcn_rcpf(s);   // v_rcp_f32
    int bin = (int)(conf * 15.0f);           // floor; conf in (1/3, 1]
    int idx = bin - BIN_LO;
    idx = idx < 0 ? 0 : (idx > RB - 1 ? RB - 1 : idx);
    float x = (p == lab) ? conf - 1.0f : conf;   // conf - accuracy
#pragma unroll
    for (int b = 0; b < RB; ++b)
        d[b] += (idx == b) ? x : 0.0f;
}

__global__ __launch_bounds__(BLOCK) void ece_main(
    const float* __restrict__ logits,
    const int* __restrict__ labels,
    float* __restrict__ part,      // [RB][GRID] partials (or RB atomics)
    long long ngroups, long long nrows, int use_atomic)
{
    float d[RB];
#pragma unroll
    for (int b = 0; b < RB; ++b) d[b] = 0.0f;

    const float4* __restrict__ L4  = (const float4*)logits;
    const int4*  __restrict__  Lb4 = (const int4*)labels;

    long long tid    = (long long)blockIdx.x * blockDim.x + threadIdx.x;
    long long stride = (long long)gridDim.x * blockDim.x;
#pragma unroll 2
    for (long long g = tid; g < ngroups; g += stride) {
        float4 a = L4[3 * g + 0];
        float4 b = L4[3 * g + 1];
        float4 c = L4[3 * g + 2];
        int4 lb  = Lb4[g];
        // rows: [a.x a.y a.z] [a.w b.x b.y] [b.z b.w c.x] [c.y c.z c.w]
        proc_row(a.x, a.y, a.z, lb.x, d);
        proc_row(a.w, b.x, b.y, lb.y, d);
        proc_row(b.z, b.w, c.x, lb.z, d);
        proc_row(c.y, c.z, c.w, lb.w, d);
    }
    // remainder rows (N % 4 != 0) — one thread
    if (tid == 0) {
        for (long long r = ngroups * 4; r < nrows; ++r)
            proc_row(logits[3 * r], logits[3 * r + 1], logits[3 * r + 2],
                     labels[r], d);
    }

    // 64-lane shuffle reduction
#pragma unroll
    for (int b = 0; b < RB; ++b)
#pragma unroll
        for (int off = 32; off > 0; off >>= 1)
            d[b] += __shfl_down(d[b], off, 64);

    __shared__ float sred[NWAVE][RB];
    int wave = threadIdx.x >> 6, lane = threadIdx.x & 63;
    if (lane == 0)
#pragma unroll
        for (int b = 0; b < RB; ++b) sred[wave][b] = d[b];
    __syncthreads();
    if (threadIdx.x < RB) {
        float v = sred[0][threadIdx.x] + sred[1][threadIdx.x] +
                  sred[2][threadIdx.x] + sred[3][threadIdx.x];
        if (use_atomic)
            atomicAdd(&part[threadIdx.x], v);
        else
            part[(long long)threadIdx.x * gridDim.x + blockIdx.x] = v;
    }
}

// Final: 1 block x 1024 threads; 2 coalesced loads per bin per thread.
__global__ __launch_bounds__(FBLOCK) void ece_final(
    const float* __restrict__ part, float* __restrict__ out,
    float invN, int use_atomic)
{
    if (use_atomic) {
        if (threadIdx.x == 0) {
            float e = 0.0f;
#pragma unroll
            for (int b = 0; b < RB; ++b) e += fabsf(part[b]);
            out[0] = e * invN;
        }
        return;
    }
    float v[RB];
#pragma unroll
    for (int b = 0; b < RB; ++b)
        v[b] = part[(long long)b * GRID + threadIdx.x] +
               part[(long long)b * GRID + FBLOCK + threadIdx.x];
#pragma unroll
    for (int b = 0; b < RB; ++b)
#pragma unroll
        for (int off = 32; off > 0; off >>= 1)
            v[b] += __shfl_down(v[b], off, 64);
    __shared__ float sred[FBLOCK / 64][RB];
    int wave = threadIdx.x >> 6, lane = threadIdx.x & 63;
    if (lane == 0)
#pragma unroll
        for (int b = 0; b < RB; ++b) sred[wave][b] = v[b];
    __syncthreads();
    if (threadIdx.x == 0) {
        float e = 0.0f;
#pragma unroll
        for (int b = 0; b < RB; ++b) {
            float t = 0.0f;
#pragma unroll
            for (int w = 0; w < FBLOCK / 64; ++w) t += sred[w][b];
            e += fabsf(t);
        }
        out[0] = e * invN;
    }
}

extern "C" void kernel_launch(void* const* d_in, const int* in_sizes, int n_in,
                              void* d_out, int out_size, void* d_ws, size_t ws_size,
                              hipStream_t stream) {
    const float* logits = (const float*)d_in[0];
    const int*   labels = (const int*)d_in[1];
    float* out  = (float*)d_out;
    float* ws   = (float*)d_ws;

    long long N = in_sizes[1];          // labels count = row count
    long long ngroups = N / 4;

    size_t need = (size_t)RB * GRID * sizeof(float);
    int use_atomic = (ws_size < need) ? 1 : 0;

    if (use_atomic)  // fallback path only: zero the 11-float accumulator
        hipMemsetAsync(ws, 0, RB * sizeof(float), stream);

    ece_main<<<GRID, BLOCK, 0, stream>>>(logits, labels, ws, ngroups, N,
                                         use_atomic);
    ece_final<<<1, FBLOCK, 0, stream>>>(ws, out, 1.0f / (float)N, use_atomic);
}